// Round 5
// baseline (179.615 us; speedup 1.0000x reference)
//
#include <hip/hip_runtime.h>

// ContextGenerator: B=32, D=NOTE_RES=64, T=4096, fp32.
// res[b,t] = sum_{L=low..min(63,up-1)} dm[b,L-1,t] * s_L[t]
// Group M (L=M+pad): s_L = P_M(pad) + sum_{k=pad}^{M-1} xC[k]*pm[k+pad].
//
// R12: dm bypasses LDS. Evidence: R7/R10/R11 (three different schedules,
// incl. channel swizzle) all ~27-30us -> neither schedule nor channel
// mapping is the limiter. Insight: rep/pm rows are reused ~3x across the six
// role-waves, but each dm row gates exactly one term -> ZERO reuse. Staging
// dm cost 1/3 of staging work + LDS for nothing (Common-mistake #7). R12 =
// R7's exact base (best measured, ~27us) with dm read directly from global
// inside the roles (256-B coalesced per wave, latency hidden under FMA+TLP);
// LDS stages only rep+pm (33.5 KB).

#define TT 4096

// Coarse-term k-range [K0, K0+8) of group32 (M=32). dm via global gdm.
template <int K0>
__device__ __forceinline__ float roleK(const float* __restrict__ lrep,
                                       const float* __restrict__ lpm,
                                       const float* __restrict__ gdm, int lane,
                                       int low, int up) {
  constexpr int PADN = (K0 + 8 < 32) ? (K0 + 8) : 32;  // pads 0..PADN-1
  constexpr int PMN = (2 * K0 + 14 < 62 ? 2 * K0 + 14 : 62) - K0 + 1;
  float xa[8];  // x1[K0..K0+7]
#pragma unroll
  for (int i = 0; i < 8; ++i)
    xa[i] = 0.5f * (lrep[(2 * (K0 + i)) * 64 + lane] +
                    lrep[(2 * (K0 + i) + 1) * 64 + lane]);
  float pmv[PMN];
#pragma unroll
  for (int r = 0; r < PMN; ++r) pmv[r] = lpm[(K0 + r) * 64 + lane];
  float res = 0.f;
#pragma unroll
  for (int pad = 0; pad < PADN; ++pad) {
    const int L = 32 + pad;
    const int kk0 = (pad > K0) ? pad : K0;
    float s = 0.f;
#pragma unroll
    for (int k = kk0; k < K0 + 8; ++k)
      s = fmaf(xa[k - K0], pmv[k + pad - K0], s);
    if (L >= low && L < up)
      res = fmaf(gdm[(size_t)(31 + pad) * TT + lane], s, res);
  }
  return res;
}

// w3: group32 coarse k in [0,8)  +  the whole M=16 level.
__device__ __forceinline__ float role3(const float* __restrict__ lrep,
                                       const float* __restrict__ lpm,
                                       const float* __restrict__ gdm, int lane,
                                       int low, int up) {
  float pmv[31];  // pm rows 0..30
#pragma unroll
  for (int r = 0; r < 31; ++r) pmv[r] = lpm[r * 64 + lane];
  float x1[32];
#pragma unroll
  for (int j = 0; j < 32; ++j)
    x1[j] = 0.5f * (lrep[(2 * j) * 64 + lane] + lrep[(2 * j + 1) * 64 + lane]);
  float res = 0.f;
#pragma unroll
  for (int pad = 0; pad < 8; ++pad) {
    const int L = 32 + pad;
    float s = 0.f;
#pragma unroll
    for (int k = pad; k < 8; ++k) s = fmaf(x1[k], pmv[k + pad], s);
    if (L >= low && L < up)
      res = fmaf(gdm[(size_t)(31 + pad) * TT + lane], s, res);
  }
  float x2[16], q1[16];
#pragma unroll
  for (int j = 0; j < 16; ++j) {
    const float a = x1[2 * j], bb = x1[2 * j + 1];
    x2[j] = 0.5f * (a + bb);
    q1[j] = a * pmv[2 * j] + bb * pmv[2 * j + 1];
  }
  float p = 0.f;
#pragma unroll
  for (int pad = 0; pad < 16; ++pad) {
    const int L = 16 + pad;
    float s = p;
#pragma unroll
    for (int k = pad; k < 16; ++k) s = fmaf(x2[k], pmv[k + pad], s);
    if (L >= low && L < up)
      res = fmaf(gdm[(size_t)(15 + pad) * TT + lane], s, res);
    p += q1[pad];
  }
  return res;
}

// w4: group32 fine-prefix duty.
__device__ __forceinline__ float role4(const float* __restrict__ lrep,
                                       const float* __restrict__ lpm,
                                       const float* __restrict__ gdm, int lane,
                                       int low, int up) {
  float res = 0.f, p = 0.f;
#pragma unroll
  for (int pad = 1; pad < 32; ++pad) {
    const int j = pad - 1;
    p = fmaf(lrep[(2 * j) * 64 + lane], lpm[(2 * j) * 64 + lane],
             fmaf(lrep[(2 * j + 1) * 64 + lane], lpm[(2 * j + 1) * 64 + lane],
                  p));
    const int L = 32 + pad;
    if (L >= low && L < up)
      res = fmaf(gdm[(size_t)(31 + pad) * TT + lane], p, res);
  }
  return res;
}

// w5: M=8,4,2,1 levels.
template <int M>
__device__ __forceinline__ void level_step(const float* pmv,
                                           const float* __restrict__ gdm,
                                           int lane, int low, int up, float* xf,
                                           float* xc, float& res) {
  float q[M];
#pragma unroll
  for (int j = 0; j < M; ++j) {
    const float a = xf[2 * j], bb = xf[2 * j + 1];
    xc[j] = 0.5f * (a + bb);
    q[j] = a * pmv[2 * j] + bb * pmv[2 * j + 1];
  }
  float p = 0.f;
#pragma unroll
  for (int pad = 0; pad < M; ++pad) {
    const int L = M + pad;
    float s = p;
#pragma unroll
    for (int k = pad; k < M; ++k) s = fmaf(xc[k], pmv[k + pad], s);
    if (L >= low && L < up)
      res = fmaf(gdm[(size_t)(M - 1 + pad) * TT + lane], s, res);
    p += q[pad];
  }
}

__device__ __forceinline__ float role5(const float* __restrict__ lrep,
                                       const float* __restrict__ lpm,
                                       const float* __restrict__ gdm, int lane,
                                       int low, int up) {
  float pmv[15];  // pm rows 0..14
#pragma unroll
  for (int r = 0; r < 15; ++r) pmv[r] = lpm[r * 64 + lane];
  float x1[32];
#pragma unroll
  for (int j = 0; j < 32; ++j)
    x1[j] = 0.5f * (lrep[(2 * j) * 64 + lane] + lrep[(2 * j + 1) * 64 + lane]);
  float x2[16];
#pragma unroll
  for (int j = 0; j < 16; ++j) x2[j] = 0.5f * (x1[2 * j] + x1[2 * j + 1]);
  float res = 0.f;
  float x3[8], x4[4], x5[2], x6[1];
  level_step<8>(pmv, gdm, lane, low, up, x2, x3, res);
  level_step<4>(pmv, gdm, lane, low, up, x3, x4, res);
  level_step<2>(pmv, gdm, lane, low, up, x4, x5, res);
  level_step<1>(pmv, gdm, lane, low, up, x5, x6, res);
  return res;
}

__global__ __launch_bounds__(384, 3) void ContextGenerator_34875134444049_kernel(
    const float* __restrict__ rep, const float* __restrict__ dm,
    const float* __restrict__ pm, const int* __restrict__ lowp,
    const int* __restrict__ upp, float* __restrict__ out) {
  // 128 data rows (64 rep | 64 pm) * 256 B + 6*64 partials = 34304 B
  __shared__ float lds[128 * 64 + 6 * 64];
  const int tid = threadIdx.x;
  const int wid = tid >> 6;
  const int lane = tid & 63;
  const int b = blockIdx.x >> 6;          // 2048 blocks: 64 chunks per batch
  const int t0 = (blockIdx.x & 63) << 6;  // 64-t slice
  const size_t base = (size_t)b * 64 * TT + (size_t)t0;

  // --- staging: rep+pm only (2048 float4 slots). Slot s: row s>>4 (0..127),
  // float4 col s&15. Rows 0..63 = rep, 64..127 = pm. dm is NOT staged.
#pragma unroll
  for (int g = 0; g < 6; ++g) {
    const int slot = tid + 384 * g;
    if (slot < 2048) {
      const int row = slot >> 4;
      const int c4 = (slot & 15) << 2;
      const float* tb = (row < 64) ? rep + base + (size_t)row * TT
                                   : pm + base + (size_t)(row - 64) * TT;
      *(float4*)(&lds[slot << 2]) = *(const float4*)(tb + c4);
    }
  }

  const int low = lowp[0];
  const int up = upp[0];

  __syncthreads();

  const float* lrep = lds;
  const float* lpm = lds + 64 * 64;
  const float* gdm = dm + base;  // dm[b, :, t0+...] read directly from global
  float* part = lds + 128 * 64;

  float res;
  if (wid == 0)
    res = roleK<24>(lrep, lpm, gdm, lane, low, up);
  else if (wid == 1)
    res = roleK<16>(lrep, lpm, gdm, lane, low, up);
  else if (wid == 2)
    res = roleK<8>(lrep, lpm, gdm, lane, low, up);
  else if (wid == 3)
    res = role3(lrep, lpm, gdm, lane, low, up);
  else if (wid == 4)
    res = role4(lrep, lpm, gdm, lane, low, up);
  else
    res = role5(lrep, lpm, gdm, lane, low, up);

  if (wid > 0) part[wid * 64 + lane] = res;
  __syncthreads();
  if (wid == 0)
    out[(size_t)b * TT + t0 + lane] = res + part[64 + lane] + part[128 + lane] +
                                      part[192 + lane] + part[256 + lane] +
                                      part[320 + lane];
}

extern "C" void kernel_launch(void* const* d_in, const int* in_sizes, int n_in,
                              void* d_out, int out_size, void* d_ws,
                              size_t ws_size, hipStream_t stream) {
  const float* rep = (const float*)d_in[0];
  const float* dm = (const float*)d_in[1];
  const float* pm = (const float*)d_in[2];
  const int* lowp = (const int*)d_in[3];
  const int* upp = (const int*)d_in[4];
  float* out = (float*)d_out;

  const int blocks = out_size / 64;  // 131072 / 64 = 2048
  ContextGenerator_34875134444049_kernel<<<blocks, 384, 0, stream>>>(
      rep, dm, pm, lowp, upp, out);
}

// Round 7
// 131.622 us; speedup vs baseline: 1.3646x; 1.3646x over previous
//
#include <hip/hip_runtime.h>

// ContextGenerator: B=32, D=NOTE_RES=64, T=4096, fp32.
// res[b,t] = sum_{L=low..min(63,up-1)} dm[b,L-1,t] * s_L[t]
// Group M (L=M+pad): s_L = P_M(pad) + sum_{k=pad}^{M-1} xC[k]*pm[k+pad].
//
// R14: dm via unconditional batched register loads; rep+pm in LDS (33.5 KB).
// R12 proved dm-direct fails ONLY when loads are branch-gated + serialized
// in the res-FMA chain (528 GB/s, VALUBusy 7%). R14 hoists each role's dm
// rows into an unrolled, compile-time-indexed register batch at role top
// (all loads issue back-to-back, one waitcnt), THEN runs gated FMAs on
// registers. Staging drops 48->32 wave-dwordx4/block (-33% of the
// barrier-serialized phase); dm's 32MB overlaps compute. R13's >64KB dynamic
// LDS never launched (absmax == ref max) - avoid >64KB LDS entirely.
// Base structure = R7 (best measured, ~27us): 2048 blocks, 384 thr, (384,3).

#define TT 4096

// Coarse-term k-range [K0, K0+8) of group32 (M=32). dm rows 31..31+PADN-1.
template <int K0>
__device__ __forceinline__ float roleK(const float* __restrict__ lrep,
                                       const float* __restrict__ lpm,
                                       const float* __restrict__ gdm, int lane,
                                       int low, int up) {
  constexpr int PADN = (K0 + 8 < 32) ? (K0 + 8) : 32;  // pads 0..PADN-1
  constexpr int PMN = (2 * K0 + 14 < 62 ? 2 * K0 + 14 : 62) - K0 + 1;
  // Unconditional dm batch: issued first, longest latency, all in flight.
  float dmv[PADN];
#pragma unroll
  for (int r = 0; r < PADN; ++r) dmv[r] = gdm[(size_t)(31 + r) * TT + lane];
  float xa[8];  // x1[K0..K0+7]
#pragma unroll
  for (int i = 0; i < 8; ++i)
    xa[i] = 0.5f * (lrep[(2 * (K0 + i)) * 64 + lane] +
                    lrep[(2 * (K0 + i) + 1) * 64 + lane]);
  float pmv[PMN];
#pragma unroll
  for (int r = 0; r < PMN; ++r) pmv[r] = lpm[(K0 + r) * 64 + lane];
  float res = 0.f;
#pragma unroll
  for (int pad = 0; pad < PADN; ++pad) {
    const int L = 32 + pad;
    const int kk0 = (pad > K0) ? pad : K0;
    float s = 0.f;
#pragma unroll
    for (int k = kk0; k < K0 + 8; ++k)
      s = fmaf(xa[k - K0], pmv[k + pad - K0], s);
    if (L >= low && L < up) res = fmaf(dmv[pad], s, res);
  }
  return res;
}

// w3: group32 coarse k in [0,8)  +  the whole M=16 level.
// dm in two batches (peak-VGPR control): rows 31..38 then rows 15..30.
__device__ __forceinline__ float role3(const float* __restrict__ lrep,
                                       const float* __restrict__ lpm,
                                       const float* __restrict__ gdm, int lane,
                                       int low, int up) {
  float dmA[8];  // rows 31..38 (group32 pads 0..7)
#pragma unroll
  for (int r = 0; r < 8; ++r) dmA[r] = gdm[(size_t)(31 + r) * TT + lane];
  float pmv[31];  // pm rows 0..30
#pragma unroll
  for (int r = 0; r < 31; ++r) pmv[r] = lpm[r * 64 + lane];
  float x1[32];
#pragma unroll
  for (int j = 0; j < 32; ++j)
    x1[j] = 0.5f * (lrep[(2 * j) * 64 + lane] + lrep[(2 * j + 1) * 64 + lane]);
  float res = 0.f;
#pragma unroll
  for (int pad = 0; pad < 8; ++pad) {
    const int L = 32 + pad;
    float s = 0.f;
#pragma unroll
    for (int k = pad; k < 8; ++k) s = fmaf(x1[k], pmv[k + pad], s);
    if (L >= low && L < up) res = fmaf(dmA[pad], s, res);
  }
  float dmB[16];  // rows 15..30 (group16 pads 0..15)
#pragma unroll
  for (int r = 0; r < 16; ++r) dmB[r] = gdm[(size_t)(15 + r) * TT + lane];
  float x2[16], q1[16];
#pragma unroll
  for (int j = 0; j < 16; ++j) {
    const float a = x1[2 * j], bb = x1[2 * j + 1];
    x2[j] = 0.5f * (a + bb);
    q1[j] = a * pmv[2 * j] + bb * pmv[2 * j + 1];
  }
  float p = 0.f;
#pragma unroll
  for (int pad = 0; pad < 16; ++pad) {
    const int L = 16 + pad;
    float s = p;
#pragma unroll
    for (int k = pad; k < 16; ++k) s = fmaf(x2[k], pmv[k + pad], s);
    if (L >= low && L < up) res = fmaf(dmB[pad], s, res);
    p += q1[pad];
  }
  return res;
}

// w4: group32 fine-prefix duty. dm rows 32..62.
__device__ __forceinline__ float role4(const float* __restrict__ lrep,
                                       const float* __restrict__ lpm,
                                       const float* __restrict__ gdm, int lane,
                                       int low, int up) {
  float dmv[31];  // rows 32..62 (pads 1..31)
#pragma unroll
  for (int r = 0; r < 31; ++r) dmv[r] = gdm[(size_t)(32 + r) * TT + lane];
  float res = 0.f, p = 0.f;
#pragma unroll
  for (int pad = 1; pad < 32; ++pad) {
    const int j = pad - 1;
    p = fmaf(lrep[(2 * j) * 64 + lane], lpm[(2 * j) * 64 + lane],
             fmaf(lrep[(2 * j + 1) * 64 + lane], lpm[(2 * j + 1) * 64 + lane],
                  p));
    const int L = 32 + pad;
    if (L >= low && L < up) res = fmaf(dmv[pad - 1], p, res);
  }
  return res;
}

// w5: M=8,4,2,1 levels. dm rows 0..14 in one batch.
template <int M>
__device__ __forceinline__ void level_step(const float* pmv, const float* dmv,
                                           int low, int up, float* xf,
                                           float* xc, float& res) {
  float q[M];
#pragma unroll
  for (int j = 0; j < M; ++j) {
    const float a = xf[2 * j], bb = xf[2 * j + 1];
    xc[j] = 0.5f * (a + bb);
    q[j] = a * pmv[2 * j] + bb * pmv[2 * j + 1];
  }
  float p = 0.f;
#pragma unroll
  for (int pad = 0; pad < M; ++pad) {
    const int L = M + pad;
    float s = p;
#pragma unroll
    for (int k = pad; k < M; ++k) s = fmaf(xc[k], pmv[k + pad], s);
    if (L >= low && L < up) res = fmaf(dmv[M - 1 + pad], s, res);
    p += q[pad];
  }
}

__device__ __forceinline__ float role5(const float* __restrict__ lrep,
                                       const float* __restrict__ lpm,
                                       const float* __restrict__ gdm, int lane,
                                       int low, int up) {
  float dmv[15];  // rows 0..14 (levels use rows M-1..2M-2)
#pragma unroll
  for (int r = 0; r < 15; ++r) dmv[r] = gdm[(size_t)r * TT + lane];
  float pmv[15];  // pm rows 0..14
#pragma unroll
  for (int r = 0; r < 15; ++r) pmv[r] = lpm[r * 64 + lane];
  float x1[32];
#pragma unroll
  for (int j = 0; j < 32; ++j)
    x1[j] = 0.5f * (lrep[(2 * j) * 64 + lane] + lrep[(2 * j + 1) * 64 + lane]);
  float x2[16];
#pragma unroll
  for (int j = 0; j < 16; ++j) x2[j] = 0.5f * (x1[2 * j] + x1[2 * j + 1]);
  float res = 0.f;
  float x3[8], x4[4], x5[2], x6[1];
  level_step<8>(pmv, dmv, low, up, x2, x3, res);
  level_step<4>(pmv, dmv, low, up, x3, x4, res);
  level_step<2>(pmv, dmv, low, up, x4, x5, res);
  level_step<1>(pmv, dmv, low, up, x5, x6, res);
  return res;
}

__global__ __launch_bounds__(384, 3) void ContextGenerator_34875134444049_kernel(
    const float* __restrict__ rep, const float* __restrict__ dm,
    const float* __restrict__ pm, const int* __restrict__ lowp,
    const int* __restrict__ upp, float* __restrict__ out) {
  // 128 data rows (64 rep | 64 pm) * 256 B + 6*64 partials = 34304 B
  __shared__ float lds[128 * 64 + 6 * 64];
  const int tid = threadIdx.x;
  const int wid = tid >> 6;
  const int lane = tid & 63;
  const int b = blockIdx.x >> 6;          // 2048 blocks: 64 chunks per batch
  const int t0 = (blockIdx.x & 63) << 6;  // 64-t slice
  const size_t base = (size_t)b * 64 * TT + (size_t)t0;

  // --- staging: rep+pm only (2048 float4 slots). Slot s: row s>>4 (0..127),
  // float4 col s&15. Rows 0..63 = rep, 64..127 = pm. dm is NOT staged.
#pragma unroll
  for (int g = 0; g < 6; ++g) {
    const int slot = tid + 384 * g;
    if (slot < 2048) {
      const int row = slot >> 4;
      const int c4 = (slot & 15) << 2;
      const float* tb = (row < 64) ? rep + base + (size_t)row * TT
                                   : pm + base + (size_t)(row - 64) * TT;
      *(float4*)(&lds[slot << 2]) = *(const float4*)(tb + c4);
    }
  }

  const int low = lowp[0];
  const int up = upp[0];

  __syncthreads();

  const float* lrep = lds;
  const float* lpm = lds + 64 * 64;
  const float* gdm = dm + base;  // dm[b, :, t0+...] direct; batched in roles
  float* part = lds + 128 * 64;

  float res;
  if (wid == 0)
    res = roleK<24>(lrep, lpm, gdm, lane, low, up);
  else if (wid == 1)
    res = roleK<16>(lrep, lpm, gdm, lane, low, up);
  else if (wid == 2)
    res = roleK<8>(lrep, lpm, gdm, lane, low, up);
  else if (wid == 3)
    res = role3(lrep, lpm, gdm, lane, low, up);
  else if (wid == 4)
    res = role4(lrep, lpm, gdm, lane, low, up);
  else
    res = role5(lrep, lpm, gdm, lane, low, up);

  if (wid > 0) part[wid * 64 + lane] = res;
  __syncthreads();
  if (wid == 0)
    out[(size_t)b * TT + t0 + lane] = res + part[64 + lane] + part[128 + lane] +
                                      part[192 + lane] + part[256 + lane] +
                                      part[320 + lane];
}

extern "C" void kernel_launch(void* const* d_in, const int* in_sizes, int n_in,
                              void* d_out, int out_size, void* d_ws,
                              size_t ws_size, hipStream_t stream) {
  const float* rep = (const float*)d_in[0];
  const float* dm = (const float*)d_in[1];
  const float* pm = (const float*)d_in[2];
  const int* lowp = (const int*)d_in[3];
  const int* upp = (const int*)d_in[4];
  float* out = (float*)d_out;

  const int blocks = out_size / 64;  // 131072 / 64 = 2048
  ContextGenerator_34875134444049_kernel<<<blocks, 384, 0, stream>>>(
      rep, dm, pm, lowp, upp, out);
}

// Round 9
// 129.851 us; speedup vs baseline: 1.3832x; 1.0136x over previous
//
#include <hip/hip_runtime.h>

// ContextGenerator: B=32, D=NOTE_RES=64, T=4096, fp32.
// res[b,t] = sum_{L=low..min(63,up-1)} dm[b,L-1,t] * s_L[t]
// Group M (L=M+pad): s_L = P_M(pad) + sum_{k=pad}^{M-1} xC[k]*pm[k+pad].
//
// R15b: identical resubmit of R15 (container failed twice = infra flake; no
// on-chip verdict). t_w=128 granularity probe INSIDE 64KB static LDS:
//   A: stage rep(64 rows)+pm(63 rows) @ 512B/row  (63.5 KB)
//   B: roles extract rep-dependent state into st[63] regs (union, static idx)
//   C: dm (63 rows, prefetched to named scalars at kernel start) overwrites
//      the rep region; pad-loops read dm from LDS. Partials overlay post-B4.
// dm-direct is dead (R12: gated-serialized 3x worse; R14: per-wave batches
// duplicate 2.2x dm traffic, +9us). Staging IS the dedupe; this keeps it and
// only doubles the contiguous run length (256B -> 512B per row-slice).
// 1024 blocks x 768 thr (12 waves: 6 roles x 2 t-halves).

#define TT 4096
#define LD 128  // t-slice width (floats)

// ---------- role prep/finish (st[] = per-thread register union) ----------

// roleK: st[0..7]=xa, st[8..8+PMN-1]=pmv.
template <int K0>
__device__ __forceinline__ void prepK(const float* __restrict__ lrep,
                                      const float* __restrict__ lpm, int li,
                                      float* st) {
  constexpr int PMN = (2 * K0 + 14 < 62 ? 2 * K0 + 14 : 62) - K0 + 1;
#pragma unroll
  for (int i = 0; i < 8; ++i)
    st[i] = 0.5f * (lrep[(2 * (K0 + i)) * LD + li] +
                    lrep[(2 * (K0 + i) + 1) * LD + li]);
#pragma unroll
  for (int r = 0; r < PMN; ++r) st[8 + r] = lpm[(K0 + r) * LD + li];
}

template <int K0>
__device__ __forceinline__ float finK(const float* __restrict__ ldm, int li,
                                      int low, int up, const float* st) {
  constexpr int PADN = (K0 + 8 < 32) ? (K0 + 8) : 32;
  float res = 0.f;
#pragma unroll
  for (int pad = 0; pad < PADN; ++pad) {
    const int L = 32 + pad;
    const int kk0 = (pad > K0) ? pad : K0;
    float s = 0.f;
#pragma unroll
    for (int k = kk0; k < K0 + 8; ++k)
      s = fmaf(st[k - K0], st[8 + k + pad - K0], s);
    if (L >= low && L < up) res = fmaf(ldm[(31 + pad) * LD + li], s, res);
  }
  return res;
}

// role3: st[0..30]=pmv rows0..30, st[31..62]=x1.
__device__ __forceinline__ void prep3(const float* __restrict__ lrep,
                                      const float* __restrict__ lpm, int li,
                                      float* st) {
#pragma unroll
  for (int r = 0; r < 31; ++r) st[r] = lpm[r * LD + li];
#pragma unroll
  for (int j = 0; j < 32; ++j)
    st[31 + j] =
        0.5f * (lrep[(2 * j) * LD + li] + lrep[(2 * j + 1) * LD + li]);
}

__device__ __forceinline__ float fin3(const float* __restrict__ ldm, int li,
                                      int low, int up, const float* st) {
  float res = 0.f;
#pragma unroll
  for (int pad = 0; pad < 8; ++pad) {
    const int L = 32 + pad;
    float s = 0.f;
#pragma unroll
    for (int k = pad; k < 8; ++k) s = fmaf(st[31 + k], st[k + pad], s);
    if (L >= low && L < up) res = fmaf(ldm[(31 + pad) * LD + li], s, res);
  }
  float x2[16], q1[16];
#pragma unroll
  for (int j = 0; j < 16; ++j) {
    const float a = st[31 + 2 * j], bb = st[31 + 2 * j + 1];
    x2[j] = 0.5f * (a + bb);
    q1[j] = a * st[2 * j] + bb * st[2 * j + 1];
  }
  float p = 0.f;
#pragma unroll
  for (int pad = 0; pad < 16; ++pad) {
    const int L = 16 + pad;
    float s = p;
#pragma unroll
    for (int k = pad; k < 16; ++k) s = fmaf(x2[k], st[k + pad], s);
    if (L >= low && L < up) res = fmaf(ldm[(15 + pad) * LD + li], s, res);
    p += q1[pad];
  }
  return res;
}

// role4: st[0..30] = prefix chain pv (pv[pad-1] = p at iteration pad).
__device__ __forceinline__ void prep4(const float* __restrict__ lrep,
                                      const float* __restrict__ lpm, int li,
                                      float* st) {
  float p = 0.f;
#pragma unroll
  for (int pad = 1; pad < 32; ++pad) {
    const int j = pad - 1;
    p = fmaf(lrep[(2 * j) * LD + li], lpm[(2 * j) * LD + li],
             fmaf(lrep[(2 * j + 1) * LD + li], lpm[(2 * j + 1) * LD + li], p));
    st[pad - 1] = p;
  }
}

__device__ __forceinline__ float fin4(const float* __restrict__ ldm, int li,
                                      int low, int up, const float* st) {
  float res = 0.f;
#pragma unroll
  for (int pad = 1; pad < 32; ++pad) {
    const int L = 32 + pad;
    if (L >= low && L < up)
      res = fmaf(ldm[(31 + pad) * LD + li], st[pad - 1], res);
  }
  return res;
}

// role5: st[0..14]=pmv rows0..14, st[15..30]=x2.
__device__ __forceinline__ void prep5(const float* __restrict__ lrep,
                                      const float* __restrict__ lpm, int li,
                                      float* st) {
#pragma unroll
  for (int r = 0; r < 15; ++r) st[r] = lpm[r * LD + li];
  float x1[32];
#pragma unroll
  for (int j = 0; j < 32; ++j)
    x1[j] = 0.5f * (lrep[(2 * j) * LD + li] + lrep[(2 * j + 1) * LD + li]);
#pragma unroll
  for (int j = 0; j < 16; ++j) st[15 + j] = 0.5f * (x1[2 * j] + x1[2 * j + 1]);
}

template <int M>
__device__ __forceinline__ void level_step(const float* pmv,
                                           const float* __restrict__ ldm,
                                           int li, int low, int up,
                                           const float* xf, float* xc,
                                           float& res) {
  float q[M];
#pragma unroll
  for (int j = 0; j < M; ++j) {
    const float a = xf[2 * j], bb = xf[2 * j + 1];
    xc[j] = 0.5f * (a + bb);
    q[j] = a * pmv[2 * j] + bb * pmv[2 * j + 1];
  }
  float p = 0.f;
#pragma unroll
  for (int pad = 0; pad < M; ++pad) {
    const int L = M + pad;
    float s = p;
#pragma unroll
    for (int k = pad; k < M; ++k) s = fmaf(xc[k], pmv[k + pad], s);
    if (L >= low && L < up) res = fmaf(ldm[(M - 1 + pad) * LD + li], s, res);
    p += q[pad];
  }
}

__device__ __forceinline__ float fin5(const float* __restrict__ ldm, int li,
                                      int low, int up, const float* st) {
  float res = 0.f;
  float x3[8], x4[4], x5[2], x6[1];
  level_step<8>(st, ldm, li, low, up, st + 15, x3, res);
  level_step<4>(st, ldm, li, low, up, x3, x4, res);
  level_step<2>(st, ldm, li, low, up, x4, x5, res);
  level_step<1>(st, ldm, li, low, up, x5, x6, res);
  return res;
}

// ---------- kernel ----------

__global__ __launch_bounds__(768, 4) void ContextGenerator_34875134444049_kernel(
    const float* __restrict__ rep, const float* __restrict__ dm,
    const float* __restrict__ pm, const int* __restrict__ lowp,
    const int* __restrict__ upp, float* __restrict__ out) {
  // 127 rows * 128 floats = 65024 B (< 64 KB static limit).
  // Phase A: rows 0..63 = rep, rows 64..126 = pm rows 0..62 (row 63 unused).
  // Phase C: rows 0..62 = dm rows 0..62 (row 63 unused). Partials overlay.
  __shared__ float lds[127 * LD];
  const int tid = threadIdx.x;
  const int wid = tid >> 6;                    // 0..11
  const int rid = wid >> 1;                    // role 0..5
  const int li = ((wid & 1) << 6) | (tid & 63);  // t-index 0..127
  const int b = blockIdx.x >> 5;               // 1024 blocks: 32 chunks/batch
  const int t0 = (blockIdx.x & 31) << 7;       // 128-t slice
  const size_t base = (size_t)b * 64 * TT + (size_t)t0;

  // dm prefetch into named scalars (R10 lesson: no aggregates). 2016 float4
  // slots (63 rows x 32); slot s: row s>>5, col4 s&31. Loads issue NOW,
  // latency hides under phase-A staging + prep.
  const int s0 = tid, s1 = tid + 768, s2 = tid + 1536;
  float4 d0 = *(const float4*)(dm + base + (size_t)(s0 >> 5) * TT +
                               ((s0 & 31) << 2));
  float4 d1 = *(const float4*)(dm + base + (size_t)(s1 >> 5) * TT +
                               ((s1 & 31) << 2));
  float4 d2;
  if (s2 < 2016)
    d2 = *(const float4*)(dm + base + (size_t)(s2 >> 5) * TT +
                          ((s2 & 31) << 2));

  // Phase A staging: rep(64)+pm(63) = 4064 float4 slots, 512B/row contiguous.
#pragma unroll
  for (int g = 0; g < 6; ++g) {
    const int slot = tid + 768 * g;
    if (slot < 4064) {
      const int row = slot >> 5;
      const int c4 = (slot & 31) << 2;
      const float* tb = (row < 64) ? rep + base + (size_t)row * TT
                                   : pm + base + (size_t)(row - 64) * TT;
      *(float4*)(&lds[slot << 2]) = *(const float4*)(tb + c4);
    }
  }

  const int low = lowp[0];
  const int up = upp[0];

  __syncthreads();  // B1: rep+pm visible

  const float* lrep = lds;
  const float* lpm = lds + 64 * LD;

  // Phase B: extract rep/pm-dependent state into registers.
  float st[63];
  if (rid == 0)
    prepK<24>(lrep, lpm, li, st);
  else if (rid == 1)
    prepK<16>(lrep, lpm, li, st);
  else if (rid == 2)
    prepK<8>(lrep, lpm, li, st);
  else if (rid == 3)
    prep3(lrep, lpm, li, st);
  else if (rid == 4)
    prep4(lrep, lpm, li, st);
  else
    prep5(lrep, lpm, li, st);

  __syncthreads();  // B2: all rep/pm LDS reads done

  // Phase C: dm overwrites the rep region.
  *(float4*)(&lds[s0 << 2]) = d0;
  *(float4*)(&lds[s1 << 2]) = d1;
  if (s2 < 2016) *(float4*)(&lds[s2 << 2]) = d2;

  __syncthreads();  // B3: dm visible

  const float* ldm = lds;  // dm rows 0..62, stride LD
  float res;
  if (rid == 0)
    res = finK<24>(ldm, li, low, up, st);
  else if (rid == 1)
    res = finK<16>(ldm, li, low, up, st);
  else if (rid == 2)
    res = finK<8>(ldm, li, low, up, st);
  else if (rid == 3)
    res = fin3(ldm, li, low, up, st);
  else if (rid == 4)
    res = fin4(ldm, li, low, up, st);
  else
    res = fin5(ldm, li, low, up, st);

  __syncthreads();  // B4: all dm LDS reads done

  float* part = lds;  // overlay partials (rows 1..5 of old dm region)
  if (rid > 0) part[rid * LD + li] = res;
  __syncthreads();  // B5: partials visible

  if (rid == 0)
    out[(size_t)b * TT + t0 + li] = res + part[1 * LD + li] +
                                    part[2 * LD + li] + part[3 * LD + li] +
                                    part[4 * LD + li] + part[5 * LD + li];
}

extern "C" void kernel_launch(void* const* d_in, const int* in_sizes, int n_in,
                              void* d_out, int out_size, void* d_ws,
                              size_t ws_size, hipStream_t stream) {
  const float* rep = (const float*)d_in[0];
  const float* dm = (const float*)d_in[1];
  const float* pm = (const float*)d_in[2];
  const int* lowp = (const int*)d_in[3];
  const int* upp = (const int*)d_in[4];
  float* out = (float*)d_out;

  const int blocks = out_size / LD;  // 131072 / 128 = 1024
  ContextGenerator_34875134444049_kernel<<<blocks, 768, 0, stream>>>(
      rep, dm, pm, lowp, upp, out);
}